// Round 1
// baseline (641.376 us; speedup 1.0000x reference)
//
#include <hip/hip_runtime.h>
#include <math.h>

typedef __bf16 bf16;
typedef bf16 bf16x8 __attribute__((ext_vector_type(8)));
typedef bf16 bf16x4 __attribute__((ext_vector_type(4)));
typedef float f32x4 __attribute__((ext_vector_type(4)));

// ---------------- workspace layout (byte offsets) ----------------
#define OFF_GLOB   0ul            // 4*32*1024 f32          = 524288
#define OFF_H      524288ul       // 8*32*256 f32            = 262144
#define OFF_SCORE  786432ul       // 8*32 f32                = 1024
#define OFF_COND   787456ul       // 8 f32 (+pad)            = 1024
#define OFF_PART   788480ul       // 4*8*32*1024 f32         = 4194304
#define OFF_PROJ   4982784ul      // 2*128*32*1024 f32       = 33554432
#define OFF_WTF2S  38537216ul     // 2*5120*1024 bf16        = 20971520
#define OFF_WTS2F  59508736ul     // 1024*1024 bf16          = 2097152
#define OFF_F0B    61605888ul     // 512*32*1024 bf16        = 33554432
#define OFF_F1B    95160320ul     // 512*32*1024 bf16        = 33554432
#define OFF_F2B    128714752ul    // 128*32*1024 bf16        = 8388608
#define OFF_F3B    137103360ul    // 128*32*1024 bf16        = 8388608
#define WS_NEED    145491968ul

// out layout: out0 @0 (512*32*1024 f32), out1 @16777216 f32, out2 @33554432 f32, out3 @37748736 f32

// ---------------- pair slots ----------------
// slot 0..3: slow->fast  (2,0)(3,0)(2,1)(3,1) ; slot 4..7: fast->slow (0,2)(1,2)(0,3)(1,3)
__device__ __forceinline__ void slot_ij(int s, int& i, int& j) {
  if (s < 4) { i = 2 + (s & 1); j = s >> 1; }
  else       { int ss = s - 4; i = ss & 1; j = 2 + (ss >> 1); }
}

// ---------------- means (+ fused bf16 conversion of all feats) ----------------
__global__ __launch_bounds__(256) void k_means_part(
    const float* __restrict__ f0, const float* __restrict__ f1,
    const float* __restrict__ f2, const float* __restrict__ f3,
    float* __restrict__ part,
    bf16* __restrict__ b0, bf16* __restrict__ b1,
    bf16* __restrict__ b2, bf16* __restrict__ b3, int do_conv)
{
  int b = blockIdx.x, c = blockIdx.y, i = blockIdx.z, tid = threadIdx.x;
  const float* f = (i == 0) ? f0 : (i == 1) ? f1 : (i == 2) ? f2 : f3;
  bf16* fb = (i == 0) ? b0 : (i == 1) ? b1 : (i == 2) ? b2 : b3;
  int chunk = (i < 2) ? 64 : 16;
  int t0 = c * chunk;
  float4 s = make_float4(0.f, 0.f, 0.f, 0.f);
  for (int t = t0; t < t0 + chunk; ++t) {
    float4 v = ((const float4*)(f + (size_t)(t * 32 + b) * 1024))[tid];
    s.x += v.x; s.y += v.y; s.z += v.z; s.w += v.w;
    if (do_conv) {
      bf16x4 o;
      o[0] = (bf16)v.x; o[1] = (bf16)v.y; o[2] = (bf16)v.z; o[3] = (bf16)v.w;
      *(bf16x4*)(fb + (size_t)(t * 32 + b) * 1024 + tid * 4) = o;
    }
  }
  ((float4*)part)[(size_t)((i * 8 + c) * 32 + b) * 256 + tid] = s;
}

__global__ __launch_bounds__(256) void k_means_final(
    const float* __restrict__ part, float* __restrict__ g)
{
  int b = blockIdx.x, i = blockIdx.y, tid = threadIdx.x;
  float4 s = make_float4(0.f, 0.f, 0.f, 0.f);
  for (int c = 0; c < 8; ++c) {
    float4 v = ((const float4*)part)[(size_t)((i * 8 + c) * 32 + b) * 256 + tid];
    s.x += v.x; s.y += v.y; s.z += v.z; s.w += v.w;
  }
  float inv = (i < 2) ? (1.f / 512.f) : (1.f / 128.f);
  s.x *= inv; s.y *= inv; s.z *= inv; s.w *= inv;
  ((float4*)g)[(size_t)(i * 32 + b) * 256 + tid] = s;
}

// ---------------- MLP layer 1 (partial, k-split, atomic accumulate) ----------------
__global__ __launch_bounds__(256) void k_mlp1(
    const float* __restrict__ g, const float* __restrict__ w1, float* __restrict__ h_ws)
{
  int s = blockIdx.x, hc = blockIdx.y, kz = blockIdx.z, tid = threadIdx.x;
  int pi, pj; slot_ij(s, pi, pj);
  int p = pi * 4 + pj;
  int h = hc * 32 + (tid & 31);
  int bg = tid >> 5;  // 0..7, handles b = bg*4 .. bg*4+3
  __shared__ float pv[32 * 65];
  float acc0 = 0.f, acc1 = 0.f, acc2 = 0.f, acc3 = 0.f;
  for (int kt = 0; kt < 8; ++kt) {
    int k0 = kz * 512 + kt * 64;
    __syncthreads();
    for (int l = tid; l < 2048; l += 256) {
      int bb = l >> 6, kk = l & 63;
      int k = k0 + kk;
      float v = (k < 1024) ? g[(size_t)pi * 32768 + bb * 1024 + k]
                           : g[(size_t)pj * 32768 + bb * 1024 + (k - 1024)];
      pv[bb * 65 + kk] = v;
    }
    __syncthreads();
    const float* wp = w1 + ((size_t)p * 2048 + k0) * 256 + hc * 32 + (tid & 31);
    for (int kk = 0; kk < 64; ++kk) {
      float w = wp[(size_t)kk * 256];
      acc0 += pv[(bg * 4 + 0) * 65 + kk] * w;
      acc1 += pv[(bg * 4 + 1) * 65 + kk] * w;
      acc2 += pv[(bg * 4 + 2) * 65 + kk] * w;
      acc3 += pv[(bg * 4 + 3) * 65 + kk] * w;
    }
  }
  atomicAdd(&h_ws[(size_t)s * 8192 + (bg * 4 + 0) * 256 + h], acc0);
  atomicAdd(&h_ws[(size_t)s * 8192 + (bg * 4 + 1) * 256 + h], acc1);
  atomicAdd(&h_ws[(size_t)s * 8192 + (bg * 4 + 2) * 256 + h], acc2);
  atomicAdd(&h_ws[(size_t)s * 8192 + (bg * 4 + 3) * 256 + h], acc3);
}

// ---------------- MLP layer 2 + sigmoid + mean + cond ----------------
__global__ __launch_bounds__(256) void k_mlp2(
    const float* __restrict__ h_ws, const float* __restrict__ b1,
    const float* __restrict__ w2, const float* __restrict__ b2,
    float* __restrict__ score, float* __restrict__ cond)
{
  int s = blockIdx.x, tid = threadIdx.x;
  int pi, pj; slot_ij(s, pi, pj);
  int p = pi * 4 + pj;
  float w2v = w2[p * 256 + tid];
  float b1v = b1[p * 256 + tid];
  float b2v = b2[p];
  __shared__ float red[4];
  float tot = 0.f;
  for (int b = 0; b < 32; ++b) {
    float v = fmaxf(h_ws[(size_t)s * 8192 + b * 256 + tid] + b1v, 0.f) * w2v;
    for (int off = 32; off > 0; off >>= 1) v += __shfl_down(v, off);
    if ((tid & 63) == 0) red[tid >> 6] = v;
    __syncthreads();
    if (tid == 0) {
      float sum = red[0] + red[1] + red[2] + red[3] + b2v;
      float sc = 1.f / (1.f + expf(-sum));
      score[s * 32 + b] = sc;
      tot += sc;
    }
    __syncthreads();
  }
  if (tid == 0) cond[s] = (tot * (1.f / 32.f) >= 0.3f) ? 1.f : 0.f;
}

// ---------------- f2s weight transpose -> B^T [co][kappa=kk*1024+ci] bf16 ----------------
__global__ __launch_bounds__(256) void k_f2s_transpose(
    const float* __restrict__ w, const float* __restrict__ cond, bf16* __restrict__ wT)
{
  int z = blockIdx.y, co = blockIdx.x, tid = threadIdx.x;  // z: output j-2
  int sel = (cond[5 + 2 * z] > 0.5f) ? 1 : ((cond[4 + 2 * z] > 0.5f) ? 0 : -1);
  if (sel < 0) return;
  int widx = sel * 2 + z;  // F2S_IDX mapping
  __shared__ float buf[5120];
  const float* src = w + ((size_t)widx * 1024 + co) * 5120;  // [co][ci][kk] row
  for (int l = tid; l < 5120; l += 256) buf[l] = src[l];
  __syncthreads();
  bf16* dst = wT + (size_t)z * 5242880 + (size_t)co * 5120;
  for (int o = tid; o < 5120; o += 256) {
    int kk = o >> 10, ci = o & 1023;
    dst[o] = (bf16)buf[ci * 5 + kk];
  }
}

// ---------------- s2f weight convert (already [co][ci]) ----------------
__global__ __launch_bounds__(256) void k_s2f_convert(
    const float* __restrict__ w, bf16* __restrict__ wT)
{
  size_t gi = (size_t)blockIdx.x * 256 + threadIdx.x;  // float4 index, 262144 total
  float4 v = ((const float4*)w)[gi];
  bf16x4 o;
  o[0] = (bf16)v.x; o[1] = (bf16)v.y; o[2] = (bf16)v.z; o[3] = (bf16)v.w;
  *(bf16x4*)&wT[gi * 4] = o;
}

// ---------------- s2f projection GEMM: proj[z][t'*32+b][co] ----------------
template<bool PRE>
__global__ __launch_bounds__(256) void k_s2f_gemm(
    const float* __restrict__ feat2, const float* __restrict__ feat3,
    const bf16* __restrict__ f2b, const bf16* __restrict__ f3b,
    const bf16* __restrict__ wT, const float* __restrict__ s2f_b,
    const float* __restrict__ cond, float* __restrict__ proj)
{
  int z = blockIdx.z;  // output j = z
  int sel = (cond[1 + 2 * z] > 0.5f) ? 3 : ((cond[2 * z] > 0.5f) ? 2 : -1);
  if (sel < 0) return;
  const float* A = (sel == 3) ? feat3 : feat2;
  const bf16* Ab = (sel == 3) ? f3b : f2b;
  float* projz = proj + (size_t)z * 4194304;
  int tid = threadIdx.x;
  // bijective XCD swizzle: each XCD gets one N-strip, sweeps all M
  int lin = blockIdx.y * 32 + blockIdx.x;
  int o_ = (lin & 7) * 32 + (lin >> 3);
  int M0 = (o_ & 31) * 128, N0 = (o_ >> 5) * 128;
  __shared__ bf16 As[128][72];
  __shared__ bf16 Bs[128][72];
  f32x4 acc[4][4];
  for (int a = 0; a < 4; ++a)
    for (int c = 0; c < 4; ++c) { acc[a][c][0] = 0.f; acc[a][c][1] = 0.f; acc[a][c][2] = 0.f; acc[a][c][3] = 0.f; }
  int row = tid >> 1, half = tid & 1;
  int lane = tid & 63, wv = tid >> 6;
  int wr = (wv >> 1) * 64, wc = (wv & 1) * 64;
  int rl = lane & 15, q = lane >> 4;
  for (int kt = 0; kt < 16; ++kt) {
    int ci0 = kt * 64;
    __syncthreads();
    if (PRE) {
      const uint4* src = (const uint4*)(Ab + (size_t)(M0 + row) * 1024 + ci0 + half * 32);
      #pragma unroll
      for (int u = 0; u < 4; ++u) *(uint4*)&As[row][half * 32 + u * 8] = src[u];
    } else {
      const float4* src = (const float4*)(A + (size_t)(M0 + row) * 1024 + ci0 + half * 32);
      #pragma unroll
      for (int u = 0; u < 4; ++u) {
        float4 v0 = src[2 * u], v1 = src[2 * u + 1];
        bf16x8 pk;
        pk[0] = (bf16)v0.x; pk[1] = (bf16)v0.y; pk[2] = (bf16)v0.z; pk[3] = (bf16)v0.w;
        pk[4] = (bf16)v1.x; pk[5] = (bf16)v1.y; pk[6] = (bf16)v1.z; pk[7] = (bf16)v1.w;
        *(bf16x8*)&As[row][half * 32 + u * 8] = pk;
      }
    }
    {
      const uint4* bs = (const uint4*)(wT + (size_t)(N0 + row) * 1024 + ci0 + half * 32);
      #pragma unroll
      for (int u = 0; u < 4; ++u) *(uint4*)&Bs[row][half * 32 + u * 8] = bs[u];
    }
    __syncthreads();
    #pragma unroll
    for (int ks = 0; ks < 2; ++ks) {
      bf16x8 af[4], bfv[4];
      #pragma unroll
      for (int mi = 0; mi < 4; ++mi) af[mi] = *(const bf16x8*)&As[wr + mi * 16 + rl][ks * 32 + q * 8];
      #pragma unroll
      for (int ni = 0; ni < 4; ++ni) bfv[ni] = *(const bf16x8*)&Bs[wc + ni * 16 + rl][ks * 32 + q * 8];
      #pragma unroll
      for (int mi = 0; mi < 4; ++mi)
        #pragma unroll
        for (int ni = 0; ni < 4; ++ni)
          acc[mi][ni] = __builtin_amdgcn_mfma_f32_16x16x32_bf16(af[mi], bfv[ni], acc[mi][ni], 0, 0, 0);
    }
  }
  #pragma unroll
  for (int mi = 0; mi < 4; ++mi)
    #pragma unroll
    for (int ni = 0; ni < 4; ++ni)
      #pragma unroll
      for (int r = 0; r < 4; ++r) {
        int gm = M0 + wr + mi * 16 + q * 4 + r;
        int gn = N0 + wc + ni * 16 + rl;
        projz[(size_t)gm * 1024 + gn] = acc[mi][ni][r] + s2f_b[gn];
      }
}

// ---------------- f2s strided-conv GEMM + residual epilogue -> out2/out3 ----------------
template<bool PRE>
__global__ __launch_bounds__(256) void k_f2s_gemm(
    const float* __restrict__ feat0, const float* __restrict__ feat1,
    const bf16* __restrict__ f0b, const bf16* __restrict__ f1b,
    const float* __restrict__ feat2, const float* __restrict__ feat3,
    const bf16* __restrict__ wT, const float* __restrict__ score,
    const float* __restrict__ cond, float* __restrict__ out)
{
  int z = blockIdx.z;  // output j = 2+z
  const float* fj = z ? feat3 : feat2;
  float* oj = out + 33554432ul + (size_t)z * 4194304;
  int tid = threadIdx.x;
  int lin = blockIdx.y * 32 + blockIdx.x;
  int o_ = (lin & 7) * 32 + (lin >> 3);
  int M0 = (o_ & 31) * 128, N0 = (o_ >> 5) * 128;
  int sel = (cond[5 + 2 * z] > 0.5f) ? 1 : ((cond[4 + 2 * z] > 0.5f) ? 0 : -1);
  if (sel < 0) {  // passthrough copy (uniform per block)
    for (int l = tid; l < 4096; l += 256) {
      int rr = l >> 5, c4 = l & 31;
      size_t idx = (size_t)(M0 + rr) * 1024 + N0 + c4 * 4;
      *(float4*)(oj + idx) = *(const float4*)(fj + idx);
    }
    return;
  }
  const float* A = sel ? feat1 : feat0;
  const bf16* Ab = sel ? f1b : f0b;
  const bf16* wTz = wT + (size_t)z * 5242880;
  int slot = (sel ? 5 : 4) + 2 * z;
  __shared__ bf16 As[128][72];
  __shared__ bf16 Bs[128][72];
  __shared__ float sld[32];
  if (tid < 32) sld[tid] = score[slot * 32 + tid];
  f32x4 acc[4][4];
  for (int a = 0; a < 4; ++a)
    for (int c = 0; c < 4; ++c) { acc[a][c][0] = 0.f; acc[a][c][1] = 0.f; acc[a][c][2] = 0.f; acc[a][c][3] = 0.f; }
  int row = tid >> 1, half = tid & 1;
  int m = M0 + row, t = m >> 5, b = m & 31;
  int lane = tid & 63, wv = tid >> 6;
  int wr = (wv >> 1) * 64, wc = (wv & 1) * 64;
  int rl = lane & 15, q = lane >> 4;
  for (int kt = 0; kt < 80; ++kt) {
    int kk = kt >> 4, ci0 = (kt & 15) << 6;
    int pos = 4 * t - 2 + kk;  // conv input position, pad=2, stride=4 (always < 512)
    __syncthreads();
    if (PRE) {
      uint4 v[4];
      if (pos >= 0) {
        const uint4* src = (const uint4*)(Ab + (size_t)(pos * 32 + b) * 1024 + ci0 + half * 32);
        #pragma unroll
        for (int u = 0; u < 4; ++u) v[u] = src[u];
      } else {
        #pragma unroll
        for (int u = 0; u < 4; ++u) v[u] = make_uint4(0u, 0u, 0u, 0u);
      }
      #pragma unroll
      for (int u = 0; u < 4; ++u) *(uint4*)&As[row][half * 32 + u * 8] = v[u];
    } else {
      float4 v[8];
      if (pos >= 0 && pos < 512) {
        const float4* src = (const float4*)(A + (size_t)(pos * 32 + b) * 1024 + ci0 + half * 32);
        #pragma unroll
        for (int u = 0; u < 8; ++u) v[u] = src[u];
      } else {
        #pragma unroll
        for (int u = 0; u < 8; ++u) v[u] = make_float4(0.f, 0.f, 0.f, 0.f);
      }
      #pragma unroll
      for (int u = 0; u < 4; ++u) {
        bf16x8 pk;
        pk[0] = (bf16)v[2 * u].x; pk[1] = (bf16)v[2 * u].y; pk[2] = (bf16)v[2 * u].z; pk[3] = (bf16)v[2 * u].w;
        pk[4] = (bf16)v[2 * u + 1].x; pk[5] = (bf16)v[2 * u + 1].y; pk[6] = (bf16)v[2 * u + 1].z; pk[7] = (bf16)v[2 * u + 1].w;
        *(bf16x8*)&As[row][half * 32 + u * 8] = pk;
      }
    }
    {
      const uint4* bs = (const uint4*)(wTz + (size_t)(N0 + row) * 5120 + kt * 64 + half * 32);
      #pragma unroll
      for (int u = 0; u < 4; ++u) *(uint4*)&Bs[row][half * 32 + u * 8] = bs[u];
    }
    __syncthreads();
    #pragma unroll
    for (int ks = 0; ks < 2; ++ks) {
      bf16x8 af[4], bfv[4];
      #pragma unroll
      for (int mi = 0; mi < 4; ++mi) af[mi] = *(const bf16x8*)&As[wr + mi * 16 + rl][ks * 32 + q * 8];
      #pragma unroll
      for (int ni = 0; ni < 4; ++ni) bfv[ni] = *(const bf16x8*)&Bs[wc + ni * 16 + rl][ks * 32 + q * 8];
      #pragma unroll
      for (int mi = 0; mi < 4; ++mi)
        #pragma unroll
        for (int ni = 0; ni < 4; ++ni)
          acc[mi][ni] = __builtin_amdgcn_mfma_f32_16x16x32_bf16(af[mi], bfv[ni], acc[mi][ni], 0, 0, 0);
    }
  }
  #pragma unroll
  for (int mi = 0; mi < 4; ++mi)
    #pragma unroll
    for (int ni = 0; ni < 4; ++ni)
      #pragma unroll
      for (int r = 0; r < 4; ++r) {
        int gm = M0 + wr + mi * 16 + q * 4 + r;
        int gn = N0 + wc + ni * 16 + rl;
        size_t idx = (size_t)gm * 1024 + gn;
        oj[idx] = fj[idx] + sld[gm & 31] * acc[mi][ni][r];
      }
}

// ---------------- interp + residual -> out0/out1 ----------------
__global__ __launch_bounds__(256) void k_interp(
    const float* __restrict__ f0, const float* __restrict__ f1,
    const float* __restrict__ proj, const float* __restrict__ score,
    const float* __restrict__ cond, float* __restrict__ out)
{
  int z = blockIdx.y, tb = blockIdx.x, tid = threadIdx.x;  // tb = t*32+b
  const float* fj = z ? f1 : f0;
  float* oj = out + (size_t)z * 16777216;
  int sel = (cond[1 + 2 * z] > 0.5f) ? 3 : ((cond[2 * z] > 0.5f) ? 2 : -1);
  float4 fv = ((const float4*)(fj + (size_t)tb * 1024))[tid];
  if (sel < 0) {
    ((float4*)(oj + (size_t)tb * 1024))[tid] = fv;
    return;
  }
  int t = tb >> 5, b = tb & 31;
  int slot = 2 * z + (sel == 3 ? 1 : 0);
  float s = score[slot * 32 + b];
  // align_corners=False linear interp, 128 -> 512: src = 0.25*t - 0.375, clipped
  float srcf = 0.25f * (float)t - 0.375f;
  srcf = fminf(fmaxf(srcf, 0.f), 127.f);
  int i0 = (int)srcf;
  int i1 = min(i0 + 1, 127);
  float w = srcf - (float)i0;
  const float* pz = proj + (size_t)z * 4194304;
  float4 a = ((const float4*)(pz + (size_t)(i0 * 32 + b) * 1024))[tid];
  float4 c = ((const float4*)(pz + (size_t)(i1 * 32 + b) * 1024))[tid];
  float4 o;
  o.x = fv.x + s * ((1.f - w) * a.x + w * c.x);
  o.y = fv.y + s * ((1.f - w) * a.y + w * c.y);
  o.z = fv.z + s * ((1.f - w) * a.z + w * c.z);
  o.w = fv.w + s * ((1.f - w) * a.w + w * c.w);
  ((float4*)(oj + (size_t)tb * 1024))[tid] = o;
}

// ---------------- launch ----------------
extern "C" void kernel_launch(void* const* d_in, const int* in_sizes, int n_in,
                              void* d_out, int out_size, void* d_ws, size_t ws_size,
                              hipStream_t stream) {
  const float* f0   = (const float*)d_in[0];
  const float* f1   = (const float*)d_in[1];
  const float* f2   = (const float*)d_in[2];
  const float* f3   = (const float*)d_in[3];
  const float* w1   = (const float*)d_in[4];
  const float* b1   = (const float*)d_in[5];
  const float* w2   = (const float*)d_in[6];
  const float* b2   = (const float*)d_in[7];
  const float* s2fw = (const float*)d_in[8];
  const float* s2fb = (const float*)d_in[9];
  const float* f2sw = (const float*)d_in[10];
  float* out = (float*)d_out;

  char* ws = (char*)d_ws;
  float* g     = (float*)(ws + OFF_GLOB);
  float* h_ws  = (float*)(ws + OFF_H);
  float* score = (float*)(ws + OFF_SCORE);
  float* cond  = (float*)(ws + OFF_COND);
  float* part  = (float*)(ws + OFF_PART);
  float* proj  = (float*)(ws + OFF_PROJ);
  bf16*  wtf   = (bf16*)(ws + OFF_WTF2S);
  bf16*  wts   = (bf16*)(ws + OFF_WTS2F);
  bf16*  f0b   = (bf16*)(ws + OFF_F0B);
  bf16*  f1b   = (bf16*)(ws + OFF_F1B);
  bf16*  f2b   = (bf16*)(ws + OFF_F2B);
  bf16*  f3b   = (bf16*)(ws + OFF_F3B);

  const bool pre = (ws_size >= WS_NEED);

  hipMemsetAsync(h_ws, 0, 262144, stream);
  if (pre)
    k_means_part<<<dim3(32, 8, 4), 256, 0, stream>>>(f0, f1, f2, f3, part, f0b, f1b, f2b, f3b, 1);
  else
    k_means_part<<<dim3(32, 8, 4), 256, 0, stream>>>(f0, f1, f2, f3, part,
                                                     (bf16*)nullptr, (bf16*)nullptr,
                                                     (bf16*)nullptr, (bf16*)nullptr, 0);
  k_means_final<<<dim3(32, 4), 256, 0, stream>>>(part, g);
  k_mlp1<<<dim3(8, 8, 4), 256, 0, stream>>>(g, w1, h_ws);
  k_mlp2<<<8, 256, 0, stream>>>(h_ws, b1, w2, b2, score, cond);
  k_f2s_transpose<<<dim3(1024, 2), 256, 0, stream>>>(f2sw, cond, wtf);
  k_s2f_convert<<<1024, 256, 0, stream>>>(s2fw, wts);
  if (pre) {
    k_s2f_gemm<true><<<dim3(32, 8, 2), 256, 0, stream>>>(f2, f3, f2b, f3b, wts, s2fb, cond, proj);
    k_f2s_gemm<true><<<dim3(32, 8, 2), 256, 0, stream>>>(f0, f1, f0b, f1b, f2, f3, wtf, score, cond, out);
  } else {
    k_s2f_gemm<false><<<dim3(32, 8, 2), 256, 0, stream>>>(f2, f3, f2b, f3b, wts, s2fb, cond, proj);
    k_f2s_gemm<false><<<dim3(32, 8, 2), 256, 0, stream>>>(f0, f1, f0b, f1b, f2, f3, wtf, score, cond, out);
  }
  k_interp<<<dim3(16384, 2), 256, 0, stream>>>(f0, f1, proj, score, cond, out);
}

// Round 2
// 626.275 us; speedup vs baseline: 1.0241x; 1.0241x over previous
//
#include <hip/hip_runtime.h>
#include <math.h>
#include <stdint.h>

typedef __bf16 bf16;
typedef bf16 bf16x8 __attribute__((ext_vector_type(8)));
typedef bf16 bf16x4 __attribute__((ext_vector_type(4)));
typedef float f32x4 __attribute__((ext_vector_type(4)));

// ---------------- workspace layout (byte offsets) ----------------
#define OFF_GLOB   0ul            // 4*32*1024 f32          = 524288
#define OFF_H      524288ul       // 8*32*256 f32            = 262144
#define OFF_SCORE  786432ul       // 8*32 f32                = 1024
#define OFF_COND   787456ul       // 8 f32 + pad; bytes [256,320) = zero scratch
#define OFF_PART   788480ul       // 4*8*32*1024 f32         = 4194304
#define OFF_PROJ   4982784ul      // 2*128*32*1024 f32       = 33554432
#define OFF_WTF2S  38537216ul     // 2*5120*1024 bf16        = 20971520
#define OFF_WTS2F  59508736ul     // 1024*1024 bf16          = 2097152
#define OFF_F0B    61605888ul     // 512*32*1024 bf16        = 33554432
#define OFF_F1B    95160320ul     // 512*32*1024 bf16        = 33554432
#define OFF_F2B    128714752ul    // 128*32*1024 bf16        = 8388608
#define OFF_F3B    137103360ul    // 128*32*1024 bf16        = 8388608
#define WS_NEED    145491968ul

// ---------------- helpers ----------------
__device__ __forceinline__ void gl2lds16(const void* g, void* lds) {
  __builtin_amdgcn_global_load_lds(
      (const __attribute__((address_space(1))) unsigned int*)g,
      (__attribute__((address_space(3))) unsigned int*)lds, 16, 0, 0);
}

// slot 0..3: slow->fast  (2,0)(3,0)(2,1)(3,1) ; slot 4..7: fast->slow (0,2)(1,2)(0,3)(1,3)
__device__ __forceinline__ void slot_ij(int s, int& i, int& j) {
  if (s < 4) { i = 2 + (s & 1); j = s >> 1; }
  else       { int ss = s - 4; i = ss & 1; j = 2 + (ss >> 1); }
}

// ---------------- means (+ fused bf16 conversion of all feats) ----------------
__global__ __launch_bounds__(256) void k_means_part(
    const float* __restrict__ f0, const float* __restrict__ f1,
    const float* __restrict__ f2, const float* __restrict__ f3,
    float* __restrict__ part,
    bf16* __restrict__ b0, bf16* __restrict__ b1,
    bf16* __restrict__ b2, bf16* __restrict__ b3, int do_conv)
{
  int b = blockIdx.x, c = blockIdx.y, i = blockIdx.z, tid = threadIdx.x;
  const float* f = (i == 0) ? f0 : (i == 1) ? f1 : (i == 2) ? f2 : f3;
  bf16* fb = (i == 0) ? b0 : (i == 1) ? b1 : (i == 2) ? b2 : b3;
  int chunk = (i < 2) ? 64 : 16;
  int t0 = c * chunk;
  float4 s = make_float4(0.f, 0.f, 0.f, 0.f);
  for (int t = t0; t < t0 + chunk; ++t) {
    float4 v = ((const float4*)(f + (size_t)(t * 32 + b) * 1024))[tid];
    s.x += v.x; s.y += v.y; s.z += v.z; s.w += v.w;
    if (do_conv) {
      bf16x4 o;
      o[0] = (bf16)v.x; o[1] = (bf16)v.y; o[2] = (bf16)v.z; o[3] = (bf16)v.w;
      *(bf16x4*)(fb + (size_t)(t * 32 + b) * 1024 + tid * 4) = o;
    }
  }
  ((float4*)part)[(size_t)((i * 8 + c) * 32 + b) * 256 + tid] = s;
}

__global__ __launch_bounds__(256) void k_means_final(
    const float* __restrict__ part, float* __restrict__ g)
{
  int b = blockIdx.x, i = blockIdx.y, tid = threadIdx.x;
  float4 s = make_float4(0.f, 0.f, 0.f, 0.f);
  for (int c = 0; c < 8; ++c) {
    float4 v = ((const float4*)part)[(size_t)((i * 8 + c) * 32 + b) * 256 + tid];
    s.x += v.x; s.y += v.y; s.z += v.z; s.w += v.w;
  }
  float inv = (i < 2) ? (1.f / 512.f) : (1.f / 128.f);
  s.x *= inv; s.y *= inv; s.z *= inv; s.w *= inv;
  ((float4*)g)[(size_t)(i * 32 + b) * 256 + tid] = s;
}

// ---------------- MLP layer 1 (partial, k-split, atomic accumulate) ----------------
__global__ __launch_bounds__(256) void k_mlp1(
    const float* __restrict__ g, const float* __restrict__ w1, float* __restrict__ h_ws)
{
  int s = blockIdx.x, hc = blockIdx.y, kz = blockIdx.z, tid = threadIdx.x;
  int pi, pj; slot_ij(s, pi, pj);
  int p = pi * 4 + pj;
  int h = hc * 32 + (tid & 31);
  int bg = tid >> 5;
  __shared__ float pv[32 * 65];
  float acc0 = 0.f, acc1 = 0.f, acc2 = 0.f, acc3 = 0.f;
  for (int kt = 0; kt < 8; ++kt) {
    int k0 = kz * 512 + kt * 64;
    __syncthreads();
    for (int l = tid; l < 2048; l += 256) {
      int bb = l >> 6, kk = l & 63;
      int k = k0 + kk;
      float v = (k < 1024) ? g[(size_t)pi * 32768 + bb * 1024 + k]
                           : g[(size_t)pj * 32768 + bb * 1024 + (k - 1024)];
      pv[bb * 65 + kk] = v;
    }
    __syncthreads();
    const float* wp = w1 + ((size_t)p * 2048 + k0) * 256 + hc * 32 + (tid & 31);
    for (int kk = 0; kk < 64; ++kk) {
      float w = wp[(size_t)kk * 256];
      acc0 += pv[(bg * 4 + 0) * 65 + kk] * w;
      acc1 += pv[(bg * 4 + 1) * 65 + kk] * w;
      acc2 += pv[(bg * 4 + 2) * 65 + kk] * w;
      acc3 += pv[(bg * 4 + 3) * 65 + kk] * w;
    }
  }
  atomicAdd(&h_ws[(size_t)s * 8192 + (bg * 4 + 0) * 256 + h], acc0);
  atomicAdd(&h_ws[(size_t)s * 8192 + (bg * 4 + 1) * 256 + h], acc1);
  atomicAdd(&h_ws[(size_t)s * 8192 + (bg * 4 + 2) * 256 + h], acc2);
  atomicAdd(&h_ws[(size_t)s * 8192 + (bg * 4 + 3) * 256 + h], acc3);
}

// ---------------- MLP layer 2 + sigmoid + mean + cond (wave-parallel over b) ----------------
__global__ __launch_bounds__(256) void k_mlp2(
    const float* __restrict__ h_ws, const float* __restrict__ b1,
    const float* __restrict__ w2, const float* __restrict__ b2,
    float* __restrict__ score, float* __restrict__ cond)
{
  int s = blockIdx.x, tid = threadIdx.x;
  int pi, pj; slot_ij(s, pi, pj);
  int p = pi * 4 + pj;
  int lane = tid & 63, wv = tid >> 6;
  float4 w2v = ((const float4*)(w2 + p * 256))[lane];
  float4 b1v = ((const float4*)(b1 + p * 256))[lane];
  float b2v = b2[p];
  __shared__ float redw[4];
  float tot = 0.f;
  for (int bb = 0; bb < 8; ++bb) {
    int b = wv * 8 + bb;
    float4 h4 = ((const float4*)(h_ws + (size_t)s * 8192 + b * 256))[lane];
    float v = fmaxf(h4.x + b1v.x, 0.f) * w2v.x + fmaxf(h4.y + b1v.y, 0.f) * w2v.y
            + fmaxf(h4.z + b1v.z, 0.f) * w2v.z + fmaxf(h4.w + b1v.w, 0.f) * w2v.w;
    #pragma unroll
    for (int off = 32; off > 0; off >>= 1) v += __shfl_down(v, off);
    if (lane == 0) {
      float sc = 1.f / (1.f + expf(-(v + b2v)));
      score[s * 32 + b] = sc;
      tot += sc;
    }
  }
  if (lane == 0) redw[wv] = tot;
  __syncthreads();
  if (tid == 0) {
    float t = redw[0] + redw[1] + redw[2] + redw[3];
    cond[s] = (t * (1.f / 32.f) >= 0.3f) ? 1.f : 0.f;
  }
}

// ---------------- f2s weight transpose -> B^T [co][kappa=kk*1024+ci] bf16 ----------------
__global__ __launch_bounds__(256) void k_f2s_transpose(
    const float* __restrict__ w, const float* __restrict__ cond, bf16* __restrict__ wT)
{
  int z = blockIdx.y, co = blockIdx.x, tid = threadIdx.x;
  int sel = (cond[5 + 2 * z] > 0.5f) ? 1 : ((cond[4 + 2 * z] > 0.5f) ? 0 : -1);
  if (sel < 0) return;
  int widx = sel * 2 + z;
  __shared__ float buf[5120];
  const float* src = w + ((size_t)widx * 1024 + co) * 5120;
  for (int l = tid; l < 5120; l += 256) buf[l] = src[l];
  __syncthreads();
  bf16* dst = wT + (size_t)z * 5242880 + (size_t)co * 5120;
  for (int o = tid; o < 5120; o += 256) {
    int kk = o >> 10, ci = o & 1023;
    dst[o] = (bf16)buf[ci * 5 + kk];
  }
}

// ---------------- s2f weight convert ----------------
__global__ __launch_bounds__(256) void k_s2f_convert(
    const float* __restrict__ w, bf16* __restrict__ wT)
{
  size_t gi = (size_t)blockIdx.x * 256 + threadIdx.x;
  float4 v = ((const float4*)w)[gi];
  bf16x4 o;
  o[0] = (bf16)v.x; o[1] = (bf16)v.y; o[2] = (bf16)v.z; o[3] = (bf16)v.w;
  *(bf16x4*)&wT[gi * 4] = o;
}

// ================= fast-path GEMMs: global_load_lds + XOR-swizzle + dbuf =================
// LDS tile [128][64] bf16 linear; chunk c in [0,1024): ldsrow = c>>3, seg = c&7.
// Swizzle: stored seg s holds global seg s^(row&7); reads use the same XOR.

// ---------------- s2f projection GEMM (K=1024) ----------------
__global__ __launch_bounds__(256) void k_s2f_gemm2(
    const bf16* __restrict__ f2b, const bf16* __restrict__ f3b,
    const bf16* __restrict__ wT, const float* __restrict__ s2f_b,
    const float* __restrict__ cond, float* __restrict__ proj)
{
  int z = blockIdx.z;
  int sel = (cond[1 + 2 * z] > 0.5f) ? 3 : ((cond[2 * z] > 0.5f) ? 2 : -1);
  if (sel < 0) return;
  const bf16* Ab = (sel == 3) ? f3b : f2b;
  float* projz = proj + (size_t)z * 4194304;
  int tid = threadIdx.x;
  int lin = blockIdx.y * 32 + blockIdx.x;
  int o_ = (lin & 7) * 32 + (lin >> 3);
  int M0 = (o_ & 31) * 128, N0 = (o_ >> 5) * 128;
  __shared__ bf16 As[2][8192];
  __shared__ bf16 Bs[2][8192];
  f32x4 acc[4][4];
  #pragma unroll
  for (int a = 0; a < 4; ++a)
    #pragma unroll
    for (int c = 0; c < 4; ++c) { acc[a][c][0] = 0.f; acc[a][c][1] = 0.f; acc[a][c][2] = 0.f; acc[a][c][3] = 0.f; }
  int lane = tid & 63, wv = tid >> 6;
  int wr = (wv >> 1) * 64, wc = (wv & 1) * 64;
  int rl = lane & 15, q = lane >> 4;
  int wb = tid & 192;  // wave-uniform chunk base

  // per-thread staging invariants
  size_t aoffs[4], boffs[4];
  #pragma unroll
  for (int rnd = 0; rnd < 4; ++rnd) {
    int c = rnd * 256 + tid, lr = c >> 3, seg = c & 7, sw = seg ^ (lr & 7);
    aoffs[rnd] = (size_t)(M0 + lr) * 1024 + sw * 8;
    boffs[rnd] = (size_t)(N0 + lr) * 1024 + sw * 8;
  }

  #define S2F_STAGE(KT, PB) {                                        \
    size_t ci0 = (size_t)(KT) * 64;                                  \
    _Pragma("unroll")                                                \
    for (int rnd = 0; rnd < 4; ++rnd) {                              \
      gl2lds16(Ab + aoffs[rnd] + ci0, &As[PB][(rnd * 256 + wb) * 8]);\
      gl2lds16(wT + boffs[rnd] + ci0, &Bs[PB][(rnd * 256 + wb) * 8]);\
    } }

  S2F_STAGE(0, 0);
  __syncthreads();
  for (int kt = 0; kt < 16; ++kt) {
    int pb = kt & 1;
    if (kt < 15) S2F_STAGE(kt + 1, pb ^ 1);
    const bf16* Ac = &As[pb][0];
    const bf16* Bc = &Bs[pb][0];
    #pragma unroll
    for (int ks = 0; ks < 2; ++ks) {
      bf16x8 af[4], bfv[4];
      #pragma unroll
      for (int mi = 0; mi < 4; ++mi) {
        int r = wr + mi * 16 + rl;
        af[mi] = *(const bf16x8*)&Ac[r * 64 + (((ks << 2) + q) ^ (r & 7)) * 8];
      }
      #pragma unroll
      for (int ni = 0; ni < 4; ++ni) {
        int r = wc + ni * 16 + rl;
        bfv[ni] = *(const bf16x8*)&Bc[r * 64 + (((ks << 2) + q) ^ (r & 7)) * 8];
      }
      #pragma unroll
      for (int mi = 0; mi < 4; ++mi)
        #pragma unroll
        for (int ni = 0; ni < 4; ++ni)
          acc[mi][ni] = __builtin_amdgcn_mfma_f32_16x16x32_bf16(af[mi], bfv[ni], acc[mi][ni], 0, 0, 0);
    }
    __syncthreads();
  }
  #pragma unroll
  for (int mi = 0; mi < 4; ++mi)
    #pragma unroll
    for (int ni = 0; ni < 4; ++ni)
      #pragma unroll
      for (int r = 0; r < 4; ++r) {
        int gm = M0 + wr + mi * 16 + q * 4 + r;
        int gn = N0 + wc + ni * 16 + rl;
        projz[(size_t)gm * 1024 + gn] = acc[mi][ni][r] + s2f_b[gn];
      }
}

// ---------------- f2s strided-conv GEMM (K=5120) + residual epilogue ----------------
__global__ __launch_bounds__(256) void k_f2s_gemm2(
    const bf16* __restrict__ f0b, const bf16* __restrict__ f1b,
    const float* __restrict__ feat2, const float* __restrict__ feat3,
    const bf16* __restrict__ wT, const float* __restrict__ score,
    const float* __restrict__ cond, const bf16* __restrict__ zbuf,
    float* __restrict__ out)
{
  int z = blockIdx.z;
  const float* fj = z ? feat3 : feat2;
  float* oj = out + 33554432ul + (size_t)z * 4194304;
  int tid = threadIdx.x;
  int lin = blockIdx.y * 32 + blockIdx.x;
  int o_ = (lin & 7) * 32 + (lin >> 3);
  int M0 = (o_ & 31) * 128, N0 = (o_ >> 5) * 128;
  int sel = (cond[5 + 2 * z] > 0.5f) ? 1 : ((cond[4 + 2 * z] > 0.5f) ? 0 : -1);
  if (sel < 0) {
    for (int l = tid; l < 4096; l += 256) {
      int rr = l >> 5, c4 = l & 31;
      size_t idx = (size_t)(M0 + rr) * 1024 + N0 + c4 * 4;
      *(float4*)(oj + idx) = *(const float4*)(fj + idx);
    }
    return;
  }
  const bf16* Ab = sel ? f1b : f0b;
  const bf16* wTz = wT + (size_t)z * 5242880;
  int slot = (sel ? 5 : 4) + 2 * z;
  __shared__ bf16 As[2][8192];
  __shared__ bf16 Bs[2][8192];
  __shared__ float sld[32];
  if (tid < 32) sld[tid] = score[slot * 32 + tid];
  f32x4 acc[4][4];
  #pragma unroll
  for (int a = 0; a < 4; ++a)
    #pragma unroll
    for (int c = 0; c < 4; ++c) { acc[a][c][0] = 0.f; acc[a][c][1] = 0.f; acc[a][c][2] = 0.f; acc[a][c][3] = 0.f; }
  int lane = tid & 63, wv = tid >> 6;
  int wr = (wv >> 1) * 64, wc = (wv & 1) * 64;
  int rl = lane & 15, q = lane >> 4;
  int wb = tid & 192;

  // per-thread staging invariants (A offset may be "negative" at t=0, guarded by t0f)
  long aoffs[4]; size_t boffs[4]; bool t0f[4];
  #pragma unroll
  for (int rnd = 0; rnd < 4; ++rnd) {
    int c = rnd * 256 + tid, lr = c >> 3, seg = c & 7, sw = seg ^ (lr & 7);
    int m = M0 + lr, t = m >> 5, b = m & 31;
    aoffs[rnd] = ((long)(4 * t - 2) * 32 + b) * 1024 + sw * 8;
    t0f[rnd] = (t == 0);
    boffs[rnd] = (size_t)(N0 + lr) * 5120 + sw * 8;
  }

  #define F2S_STAGE(KT, PB) {                                                   \
    int kk_ = (KT) >> 4;                                                        \
    long aadd_ = (long)kk_ * 32768 + (((KT) & 15) << 6);                        \
    size_t badd_ = (size_t)(KT) * 64;                                           \
    bool zk_ = (kk_ < 2);                                                       \
    _Pragma("unroll")                                                           \
    for (int rnd = 0; rnd < 4; ++rnd) {                                         \
      const bf16* sA = (zk_ && t0f[rnd]) ? zbuf : (Ab + aoffs[rnd] + aadd_);    \
      gl2lds16(sA, &As[PB][(rnd * 256 + wb) * 8]);                              \
      gl2lds16(wTz + boffs[rnd] + badd_, &Bs[PB][(rnd * 256 + wb) * 8]);        \
    } }

  F2S_STAGE(0, 0);
  __syncthreads();
  for (int kt = 0; kt < 80; ++kt) {
    int pb = kt & 1;
    if (kt < 79) F2S_STAGE(kt + 1, pb ^ 1);
    const bf16* Ac = &As[pb][0];
    const bf16* Bc = &Bs[pb][0];
    #pragma unroll
    for (int ks = 0; ks < 2; ++ks) {
      bf16x8 af[4], bfv[4];
      #pragma unroll
      for (int mi = 0; mi < 4; ++mi) {
        int r = wr + mi * 16 + rl;
        af[mi] = *(const bf16x8*)&Ac[r * 64 + (((ks << 2) + q) ^ (r & 7)) * 8];
      }
      #pragma unroll
      for (int ni = 0; ni < 4; ++ni) {
        int r = wc + ni * 16 + rl;
        bfv[ni] = *(const bf16x8*)&Bc[r * 64 + (((ks << 2) + q) ^ (r & 7)) * 8];
      }
      #pragma unroll
      for (int mi = 0; mi < 4; ++mi)
        #pragma unroll
        for (int ni = 0; ni < 4; ++ni)
          acc[mi][ni] = __builtin_amdgcn_mfma_f32_16x16x32_bf16(af[mi], bfv[ni], acc[mi][ni], 0, 0, 0);
    }
    __syncthreads();
  }
  #pragma unroll
  for (int mi = 0; mi < 4; ++mi)
    #pragma unroll
    for (int ni = 0; ni < 4; ++ni)
      #pragma unroll
      for (int r = 0; r < 4; ++r) {
        int gm = M0 + wr + mi * 16 + q * 4 + r;
        int gn = N0 + wc + ni * 16 + rl;
        size_t idx = (size_t)gm * 1024 + gn;
        oj[idx] = fj[idx] + sld[gm & 31] * acc[mi][ni][r];
      }
}

// ================= fallback GEMMs (f32 reg-staging, used when ws too small) =================
__global__ __launch_bounds__(256) void k_s2f_gemm_fb(
    const float* __restrict__ feat2, const float* __restrict__ feat3,
    const bf16* __restrict__ wT, const float* __restrict__ s2f_b,
    const float* __restrict__ cond, float* __restrict__ proj)
{
  int z = blockIdx.z;
  int sel = (cond[1 + 2 * z] > 0.5f) ? 3 : ((cond[2 * z] > 0.5f) ? 2 : -1);
  if (sel < 0) return;
  const float* A = (sel == 3) ? feat3 : feat2;
  float* projz = proj + (size_t)z * 4194304;
  int tid = threadIdx.x;
  int lin = blockIdx.y * 32 + blockIdx.x;
  int o_ = (lin & 7) * 32 + (lin >> 3);
  int M0 = (o_ & 31) * 128, N0 = (o_ >> 5) * 128;
  __shared__ bf16 As[128][72];
  __shared__ bf16 Bs[128][72];
  f32x4 acc[4][4];
  for (int a = 0; a < 4; ++a)
    for (int c = 0; c < 4; ++c) { acc[a][c][0] = 0.f; acc[a][c][1] = 0.f; acc[a][c][2] = 0.f; acc[a][c][3] = 0.f; }
  int row = tid >> 1, half = tid & 1;
  int lane = tid & 63, wv = tid >> 6;
  int wr = (wv >> 1) * 64, wc = (wv & 1) * 64;
  int rl = lane & 15, q = lane >> 4;
  for (int kt = 0; kt < 16; ++kt) {
    int ci0 = kt * 64;
    __syncthreads();
    {
      const float4* src = (const float4*)(A + (size_t)(M0 + row) * 1024 + ci0 + half * 32);
      #pragma unroll
      for (int u = 0; u < 4; ++u) {
        float4 v0 = src[2 * u], v1 = src[2 * u + 1];
        bf16x8 pk;
        pk[0] = (bf16)v0.x; pk[1] = (bf16)v0.y; pk[2] = (bf16)v0.z; pk[3] = (bf16)v0.w;
        pk[4] = (bf16)v1.x; pk[5] = (bf16)v1.y; pk[6] = (bf16)v1.z; pk[7] = (bf16)v1.w;
        *(bf16x8*)&As[row][half * 32 + u * 8] = pk;
      }
      const uint4* bs = (const uint4*)(wT + (size_t)(N0 + row) * 1024 + ci0 + half * 32);
      #pragma unroll
      for (int u = 0; u < 4; ++u) *(uint4*)&Bs[row][half * 32 + u * 8] = bs[u];
    }
    __syncthreads();
    #pragma unroll
    for (int ks = 0; ks < 2; ++ks) {
      bf16x8 af[4], bfv[4];
      #pragma unroll
      for (int mi = 0; mi < 4; ++mi) af[mi] = *(const bf16x8*)&As[wr + mi * 16 + rl][ks * 32 + q * 8];
      #pragma unroll
      for (int ni = 0; ni < 4; ++ni) bfv[ni] = *(const bf16x8*)&Bs[wc + ni * 16 + rl][ks * 32 + q * 8];
      #pragma unroll
      for (int mi = 0; mi < 4; ++mi)
        #pragma unroll
        for (int ni = 0; ni < 4; ++ni)
          acc[mi][ni] = __builtin_amdgcn_mfma_f32_16x16x32_bf16(af[mi], bfv[ni], acc[mi][ni], 0, 0, 0);
    }
  }
  #pragma unroll
  for (int mi = 0; mi < 4; ++mi)
    #pragma unroll
    for (int ni = 0; ni < 4; ++ni)
      #pragma unroll
      for (int r = 0; r < 4; ++r) {
        int gm = M0 + wr + mi * 16 + q * 4 + r;
        int gn = N0 + wc + ni * 16 + rl;
        projz[(size_t)gm * 1024 + gn] = acc[mi][ni][r] + s2f_b[gn];
      }
}

__global__ __launch_bounds__(256) void k_f2s_gemm_fb(
    const float* __restrict__ feat0, const float* __restrict__ feat1,
    const float* __restrict__ feat2, const float* __restrict__ feat3,
    const bf16* __restrict__ wT, const float* __restrict__ score,
    const float* __restrict__ cond, float* __restrict__ out)
{
  int z = blockIdx.z;
  const float* fj = z ? feat3 : feat2;
  float* oj = out + 33554432ul + (size_t)z * 4194304;
  int tid = threadIdx.x;
  int lin = blockIdx.y * 32 + blockIdx.x;
  int o_ = (lin & 7) * 32 + (lin >> 3);
  int M0 = (o_ & 31) * 128, N0 = (o_ >> 5) * 128;
  int sel = (cond[5 + 2 * z] > 0.5f) ? 1 : ((cond[4 + 2 * z] > 0.5f) ? 0 : -1);
  if (sel < 0) {
    for (int l = tid; l < 4096; l += 256) {
      int rr = l >> 5, c4 = l & 31;
      size_t idx = (size_t)(M0 + rr) * 1024 + N0 + c4 * 4;
      *(float4*)(oj + idx) = *(const float4*)(fj + idx);
    }
    return;
  }
  const float* A = sel ? feat1 : feat0;
  const bf16* wTz = wT + (size_t)z * 5242880;
  int slot = (sel ? 5 : 4) + 2 * z;
  __shared__ bf16 As[128][72];
  __shared__ bf16 Bs[128][72];
  __shared__ float sld[32];
  if (tid < 32) sld[tid] = score[slot * 32 + tid];
  f32x4 acc[4][4];
  for (int a = 0; a < 4; ++a)
    for (int c = 0; c < 4; ++c) { acc[a][c][0] = 0.f; acc[a][c][1] = 0.f; acc[a][c][2] = 0.f; acc[a][c][3] = 0.f; }
  int row = tid >> 1, half = tid & 1;
  int m = M0 + row, t = m >> 5, b = m & 31;
  int lane = tid & 63, wv = tid >> 6;
  int wr = (wv >> 1) * 64, wc = (wv & 1) * 64;
  int rl = lane & 15, q = lane >> 4;
  for (int kt = 0; kt < 80; ++kt) {
    int kk = kt >> 4, ci0 = (kt & 15) << 6;
    int pos = 4 * t - 2 + kk;
    __syncthreads();
    {
      float4 v[8];
      if (pos >= 0 && pos < 512) {
        const float4* src = (const float4*)(A + (size_t)(pos * 32 + b) * 1024 + ci0 + half * 32);
        #pragma unroll
        for (int u = 0; u < 8; ++u) v[u] = src[u];
      } else {
        #pragma unroll
        for (int u = 0; u < 8; ++u) v[u] = make_float4(0.f, 0.f, 0.f, 0.f);
      }
      #pragma unroll
      for (int u = 0; u < 4; ++u) {
        bf16x8 pk;
        pk[0] = (bf16)v[2 * u].x; pk[1] = (bf16)v[2 * u].y; pk[2] = (bf16)v[2 * u].z; pk[3] = (bf16)v[2 * u].w;
        pk[4] = (bf16)v[2 * u + 1].x; pk[5] = (bf16)v[2 * u + 1].y; pk[6] = (bf16)v[2 * u + 1].z; pk[7] = (bf16)v[2 * u + 1].w;
        *(bf16x8*)&As[row][half * 32 + u * 8] = pk;
      }
      const uint4* bs = (const uint4*)(wTz + (size_t)(N0 + row) * 5120 + kt * 64 + half * 32);
      #pragma unroll
      for (int u = 0; u < 4; ++u) *(uint4*)&Bs[row][half * 32 + u * 8] = bs[u];
    }
    __syncthreads();
    #pragma unroll
    for (int ks = 0; ks < 2; ++ks) {
      bf16x8 af[4], bfv[4];
      #pragma unroll
      for (int mi = 0; mi < 4; ++mi) af[mi] = *(const bf16x8*)&As[wr + mi * 16 + rl][ks * 32 + q * 8];
      #pragma unroll
      for (int ni = 0; ni < 4; ++ni) bfv[ni] = *(const bf16x8*)&Bs[wc + ni * 16 + rl][ks * 32 + q * 8];
      #pragma unroll
      for (int mi = 0; mi < 4; ++mi)
        #pragma unroll
        for (int ni = 0; ni < 4; ++ni)
          acc[mi][ni] = __builtin_amdgcn_mfma_f32_16x16x32_bf16(af[mi], bfv[ni], acc[mi][ni], 0, 0, 0);
    }
  }
  #pragma unroll
  for (int mi = 0; mi < 4; ++mi)
    #pragma unroll
    for (int ni = 0; ni < 4; ++ni)
      #pragma unroll
      for (int r = 0; r < 4; ++r) {
        int gm = M0 + wr + mi * 16 + q * 4 + r;
        int gn = N0 + wc + ni * 16 + rl;
        size_t idx = (size_t)gm * 1024 + gn;
        oj[idx] = fj[idx] + sld[gm & 31] * acc[mi][ni][r];
      }
}

// ---------------- interp + residual -> out0/out1 ----------------
__global__ __launch_bounds__(256) void k_interp(
    const float* __restrict__ f0, const float* __restrict__ f1,
    const float* __restrict__ proj, const float* __restrict__ score,
    const float* __restrict__ cond, float* __restrict__ out)
{
  int z = blockIdx.y, tb = blockIdx.x, tid = threadIdx.x;
  const float* fj = z ? f1 : f0;
  float* oj = out + (size_t)z * 16777216;
  int sel = (cond[1 + 2 * z] > 0.5f) ? 3 : ((cond[2 * z] > 0.5f) ? 2 : -1);
  float4 fv = ((const float4*)(fj + (size_t)tb * 1024))[tid];
  if (sel < 0) {
    ((float4*)(oj + (size_t)tb * 1024))[tid] = fv;
    return;
  }
  int t = tb >> 5, b = tb & 31;
  int slot = 2 * z + (sel == 3 ? 1 : 0);
  float s = score[slot * 32 + b];
  float srcf = 0.25f * (float)t - 0.375f;
  srcf = fminf(fmaxf(srcf, 0.f), 127.f);
  int i0 = (int)srcf;
  int i1 = min(i0 + 1, 127);
  float w = srcf - (float)i0;
  const float* pz = proj + (size_t)z * 4194304;
  float4 a = ((const float4*)(pz + (size_t)(i0 * 32 + b) * 1024))[tid];
  float4 c = ((const float4*)(pz + (size_t)(i1 * 32 + b) * 1024))[tid];
  float4 o;
  o.x = fv.x + s * ((1.f - w) * a.x + w * c.x);
  o.y = fv.y + s * ((1.f - w) * a.y + w * c.y);
  o.z = fv.z + s * ((1.f - w) * a.z + w * c.z);
  o.w = fv.w + s * ((1.f - w) * a.w + w * c.w);
  ((float4*)(oj + (size_t)tb * 1024))[tid] = o;
}

// ---------------- launch ----------------
extern "C" void kernel_launch(void* const* d_in, const int* in_sizes, int n_in,
                              void* d_out, int out_size, void* d_ws, size_t ws_size,
                              hipStream_t stream) {
  const float* f0   = (const float*)d_in[0];
  const float* f1   = (const float*)d_in[1];
  const float* f2   = (const float*)d_in[2];
  const float* f3   = (const float*)d_in[3];
  const float* w1   = (const float*)d_in[4];
  const float* b1   = (const float*)d_in[5];
  const float* w2   = (const float*)d_in[6];
  const float* b2   = (const float*)d_in[7];
  const float* s2fw = (const float*)d_in[8];
  const float* s2fb = (const float*)d_in[9];
  const float* f2sw = (const float*)d_in[10];
  float* out = (float*)d_out;

  char* ws = (char*)d_ws;
  float* g     = (float*)(ws + OFF_GLOB);
  float* h_ws  = (float*)(ws + OFF_H);
  float* score = (float*)(ws + OFF_SCORE);
  float* cond  = (float*)(ws + OFF_COND);
  bf16*  zbuf  = (bf16*)(ws + OFF_COND + 256);
  float* part  = (float*)(ws + OFF_PART);
  float* proj  = (float*)(ws + OFF_PROJ);
  bf16*  wtf   = (bf16*)(ws + OFF_WTF2S);
  bf16*  wts   = (bf16*)(ws + OFF_WTS2F);
  bf16*  f0b   = (bf16*)(ws + OFF_F0B);
  bf16*  f1b   = (bf16*)(ws + OFF_F1B);
  bf16*  f2b   = (bf16*)(ws + OFF_F2B);
  bf16*  f3b   = (bf16*)(ws + OFF_F3B);

  const bool pre = (ws_size >= WS_NEED);

  hipMemsetAsync(h_ws, 0, 262144, stream);
  hipMemsetAsync(ws + OFF_COND + 256, 0, 64, stream);
  if (pre)
    k_means_part<<<dim3(32, 8, 4), 256, 0, stream>>>(f0, f1, f2, f3, part, f0b, f1b, f2b, f3b, 1);
  else
    k_means_part<<<dim3(32, 8, 4), 256, 0, stream>>>(f0, f1, f2, f3, part,
                                                     (bf16*)nullptr, (bf16*)nullptr,
                                                     (bf16*)nullptr, (bf16*)nullptr, 0);
  k_means_final<<<dim3(32, 4), 256, 0, stream>>>(part, g);
  k_mlp1<<<dim3(8, 8, 4), 256, 0, stream>>>(g, w1, h_ws);
  k_mlp2<<<8, 256, 0, stream>>>(h_ws, b1, w2, b2, score, cond);
  k_f2s_transpose<<<dim3(1024, 2), 256, 0, stream>>>(f2sw, cond, wtf);
  k_s2f_convert<<<1024, 256, 0, stream>>>(s2fw, wts);
  if (pre) {
    k_s2f_gemm2<<<dim3(32, 8, 2), 256, 0, stream>>>(f2b, f3b, wts, s2fb, cond, proj);
    k_f2s_gemm2<<<dim3(32, 8, 2), 256, 0, stream>>>(f0b, f1b, f2, f3, wtf, score, cond, zbuf, out);
  } else {
    k_s2f_gemm_fb<<<dim3(32, 8, 2), 256, 0, stream>>>(f2, f3, wts, s2fb, cond, proj);
    k_f2s_gemm_fb<<<dim3(32, 8, 2), 256, 0, stream>>>(f0, f1, f2, f3, wtf, score, cond, out);
  }
  k_interp<<<dim3(16384, 2), 256, 0, stream>>>(f0, f1, proj, score, cond, out);
}